// Round 6
// baseline (386.454 us; speedup 1.0000x reference)
//
#include <hip/hip_runtime.h>
#include <hip/hip_fp16.h>
#include <cstdint>
#include <cstddef>

// GCNClassifier: 2x AGNNConv(D=320) -> marker weight -> BN+LeakyReLU ->
// softmax @ ref_center -> 2x AGNNConv(D=16) -> row softmax.
// N=50000, E=300000 (incl. self-loops => every dst segment non-empty).
//
// R9:
//  - depth-2 software pipeline in both conv gather loops (two row buffers,
//    2-step statically-unrolled body; edge t computes while t+2's loads are
//    in flight). R8's depth-1 still exposed edge-0 latency per chunk and
//    kept only one row in flight (eff. BW 2.7 TB/s < 3.6 the f32 kernel hit).
//  - launch diet 17 -> 14 kernels: cursor/stats init folded into scan1;
//    scan2 + scan_buckets merged (65-block kernel); scan_hist folded into
//    scan3; bn_finalize folded into bn_apply_p (per-block recompute).
// Kept: fp16 gather storage, 16-lane groups, hoisted inverse norms, fixed
// softmax shift M=|beta|, descending-degree (LPT) counting sort,
// register-resident bn_apply_p.

#define D_BIG 320

__device__ __forceinline__ float dot4(float4 a, float4 b) {
    return a.x * b.x + a.y * b.y + a.z * b.z + a.w * b.w;
}

// fp16 quad <-> float4 (8 bytes per lane-element)
union h4u { uint2 u; __half2 h[2]; };

__device__ __forceinline__ float4 h4_to_f4(uint2 raw) {
    h4u pk; pk.u = raw;
    float2 lo = __half22float2(pk.h[0]);
    float2 hi = __half22float2(pk.h[1]);
    return float4{lo.x, lo.y, hi.x, hi.y};
}

__device__ __forceinline__ uint2 f4_to_h4(float4 v) {
    h4u pk;
    pk.h[0] = __floats2half2_rn(v.x, v.y);
    pk.h[1] = __floats2half2_rn(v.z, v.w);
    return pk.u;
}

__global__ void fill_u32(unsigned* p, unsigned v, int n) {
    int i = blockIdx.x * blockDim.x + threadIdx.x;
    if (i < n) p[i] = v;
}

// ---------------- CSR build (dst-major) ----------------
__global__ void count_deg(const int* __restrict__ dst, unsigned* __restrict__ deg, int nE) {
    int k = blockIdx.x * blockDim.x + threadIdx.x;
    if (k < nE) atomicAdd(&deg[dst[k]], 1u);
}

// Block-local exclusive scan of deg + per-block degree histogram (descending
// bins, LPT) + cursor init + stats zero.
__global__ void scan1(const unsigned* __restrict__ deg, unsigned* __restrict__ rs,
                      unsigned* __restrict__ bsum, unsigned* __restrict__ blockhist,
                      unsigned* __restrict__ cursor, float* __restrict__ stats,
                      int n, int nb) {
    __shared__ unsigned buf[256];
    __shared__ unsigned lh[64];
    if (threadIdx.x < 64) lh[threadIdx.x] = 0u;
    int i = blockIdx.x * 256 + threadIdx.x;
    unsigned v = (i < n) ? deg[i] : 0u;
    buf[threadIdx.x] = v;
    __syncthreads();
    if (i < n) {
        atomicAdd(&lh[63u - min(v, 63u)], 1u);   // LPT: big degrees first
        cursor[i] = 0u;
    }
    if (blockIdx.x == 0 && threadIdx.x < 64) stats[threadIdx.x] = 0.f;
    for (int off = 1; off < 256; off <<= 1) {
        unsigned t = (threadIdx.x >= (unsigned)off) ? buf[threadIdx.x - off] : 0u;
        __syncthreads();
        buf[threadIdx.x] += t;
        __syncthreads();
    }
    if (i < n) rs[i] = buf[threadIdx.x] - v;           // exclusive
    if (threadIdx.x == 255) bsum[blockIdx.x] = buf[255];
    __syncthreads();
    if (threadIdx.x < 64) blockhist[threadIdx.x * nb + blockIdx.x] = lh[threadIdx.x];
}

// Blocks 0..63: per-bucket exclusive scan of blockhist (+ bucket totals).
// Block 64: exclusive scan of bsum. (Independent inputs, both from scan1.)
__global__ void scan2b(unsigned* __restrict__ bsum, unsigned* __restrict__ blockhist,
                       unsigned* __restrict__ btot, int nb) {
    __shared__ unsigned buf[256];
    int k = threadIdx.x;
    if (blockIdx.x == 64) {
        unsigned v = (k < nb) ? bsum[k] : 0u;
        buf[k] = v;
        __syncthreads();
        for (int off = 1; off < 256; off <<= 1) {
            unsigned t = (k >= off) ? buf[k - off] : 0u;
            __syncthreads();
            buf[k] += t;
            __syncthreads();
        }
        if (k < nb) bsum[k] = buf[k] - v;             // exclusive
    } else {
        int b = blockIdx.x;                           // bucket
        unsigned v = (k < nb) ? blockhist[b * nb + k] : 0u;
        buf[k] = v;
        __syncthreads();
        for (int off = 1; off < 256; off <<= 1) {
            unsigned t = (k >= off) ? buf[k - off] : 0u;
            __syncthreads();
            buf[k] += t;
            __syncthreads();
        }
        if (k < nb) blockhist[b * nb + k] = buf[k] - v;   // exclusive within bucket
        if (k == 255) btot[b] = buf[255];                 // bucket total
    }
}

// Blocks 0..nb-1: finalize rowstart. Block nb: exclusive scan of btot -> bases.
__global__ void scan3b(unsigned* __restrict__ rs, const unsigned* __restrict__ bsum,
                       unsigned* __restrict__ btot, int n, int nE, int nb) {
    if ((int)blockIdx.x == nb) {
        if (threadIdx.x < 64) {
            int t = threadIdx.x;
            unsigned v = btot[t];
            unsigned p = v;
            #pragma unroll
            for (int off = 1; off < 64; off <<= 1) {
                unsigned o = __shfl_up(p, off, 64);
                if (t >= off) p += o;
            }
            btot[t] = p - v;   // exclusive
        }
        return;
    }
    int i = blockIdx.x * 256 + threadIdx.x;
    if (i < n) rs[i] += bsum[blockIdx.x];
    if (i == 0) rs[n] = (unsigned)nE;
}

__global__ void scatter_edges(const int* __restrict__ src, const int* __restrict__ dst,
                              const unsigned* __restrict__ rowstart, unsigned* __restrict__ cursor,
                              int* __restrict__ esrc, int nE) {
    int k = blockIdx.x * blockDim.x + threadIdx.x;
    if (k >= nE) return;
    int t = dst[k];
    unsigned pos = rowstart[t] + atomicAdd(&cursor[t], 1u);
    esrc[pos] = src[k];
}

__global__ void place2(const unsigned* __restrict__ deg, const unsigned* __restrict__ blockhist,
                       const unsigned* __restrict__ bbase, int* __restrict__ perm,
                       int n, int nb) {
    __shared__ unsigned lc[64];
    if (threadIdx.x < 64) lc[threadIdx.x] = 0u;
    __syncthreads();
    int i = blockIdx.x * 256 + threadIdx.x;
    if (i < n) {
        unsigned bin  = 63u - min(deg[i], 63u);       // LPT: descending degree
        unsigned rank = atomicAdd(&lc[bin], 1u);
        unsigned pos  = bbase[bin] + blockhist[bin * nb + blockIdx.x] + rank;
        perm[pos] = i;
    }
}

// -------- prep: inverse L2 norm of x rows + f32 -> fp16 cast --------
__global__ void prep_x(const float* __restrict__ x, uint2* __restrict__ xh,
                       float* __restrict__ invn, int n) {
    int g    = (blockIdx.x * blockDim.x + threadIdx.x) >> 4;
    int lane = threadIdx.x & 15;
    if (g >= n) return;
    const float4* p = (const float4*)(x + (size_t)g * D_BIG);
    uint2* ph = xh + (size_t)g * 80;          // 320 halves = 80 uint2
    float s2 = 0.f;
    #pragma unroll
    for (int q = 0; q < 5; q++) {
        float4 v = p[lane + 16 * q];
        s2 += dot4(v, v);
        ph[lane + 16 * q] = f4_to_h4(v);
    }
    #pragma unroll
    for (int m = 8; m >= 1; m >>= 1) s2 += __shfl_xor(s2, m, 16);
    if (lane == 0) invn[g] = 1.f / fmaxf(sqrtf(s2), 1e-12f);
}

// ---------------- fused AGNNConv D=320, 16-lane group per node ----------------
// fp16 rows (80 uint2/row); depth-2 software pipeline (2 rows in flight).
// EPI: 0 = write fp16 aggregate + its inverse norm; 1 = f32 marker-weight + f
template <int EPI>
__global__ void agnn_big(const uint2* __restrict__ h,     // fp16 rows
                         const unsigned* __restrict__ rowstart,
                         const int* __restrict__ esrc,
                         const int* __restrict__ perm,
                         const float* __restrict__ beta,
                         const float* __restrict__ inv_in,
                         const float* __restrict__ mw,    // EPI==1
                         float* __restrict__ out,         // EPI==1 (f32 fea)
                         uint2* __restrict__ out_h,       // EPI==0 (fp16 h1)
                         float* __restrict__ inv_out,     // EPI==0
                         float* __restrict__ f_out,       // EPI==1
                         int n) {
    int g    = (blockIdx.x * blockDim.x + threadIdx.x) >> 4;
    int lane = threadIdx.x & 15;
    if (g >= n) return;
    int node = perm[g];
    unsigned r0 = rowstart[node], r1 = rowstart[node + 1];
    float b0 = beta[0];
    float M  = fabsf(b0);            // |score| <= |b0| (cosine in [-1,1], temp=1)
    float bs = b0 * inv_in[node];    // score = bs * inv_n[src] * (h_s . h_d)

    const uint2* pd = h + (size_t)node * 80;
    float4 d[5];
    #pragma unroll
    for (int q = 0; q < 5; q++) d[q] = h4_to_f4(pd[lane + 16 * q]);

    float4 a[5];
    #pragma unroll
    for (int q = 0; q < 5; q++) a[q] = float4{0.f, 0.f, 0.f, 0.f};
    float lrun = 0.f;

    auto edge_compute = [&](const uint2 (&rr)[5], float ins) {
        float4 r[5];
        #pragma unroll
        for (int q = 0; q < 5; q++) r[q] = h4_to_f4(rr[q]);
        float dt = 0.f;
        #pragma unroll
        for (int q = 0; q < 5; q++) dt += dot4(r[q], d[q]);
        #pragma unroll
        for (int m = 8; m >= 1; m >>= 1) dt += __shfl_xor(dt, m, 16);
        float w = __expf(bs * ins * dt - M);
        lrun += w;
        #pragma unroll
        for (int q = 0; q < 5; q++) {
            a[q].x += w * r[q].x; a[q].y += w * r[q].y;
            a[q].z += w * r[q].z; a[q].w += w * r[q].w;
        }
    };

    for (unsigned base = r0; base < r1; base += 16) {
        unsigned j = base + (unsigned)lane;
        bool  vld = j < r1;
        int   sv  = vld ? esrc[j] : 0;
        float iv  = vld ? inv_in[sv] : 0.f;
        int cnt = (int)min(r1 - base, 16u);

        uint2 ra[5], rb[5];
        {   // prime edges 0 and 1
            int s0 = __shfl(sv, 0, 16);
            const uint2* p0 = h + (size_t)s0 * 80;
            #pragma unroll
            for (int q = 0; q < 5; q++) ra[q] = p0[lane + 16 * q];
            int s1 = __shfl(sv, (cnt > 1) ? 1 : 0, 16);
            const uint2* p1 = h + (size_t)s1 * 80;
            if (cnt > 1) {
                #pragma unroll
                for (int q = 0; q < 5; q++) rb[q] = p1[lane + 16 * q];
            }
        }

        #pragma unroll 1
        for (int t = 0; t < cnt; t += 2) {
            // phase A: compute edge t (ra) while loading edge t+2
            {
                uint2 nx[5];
                bool pf = (t + 2) < cnt;
                int sA = __shfl(sv, pf ? t + 2 : 0, 16);
                const uint2* pA = h + (size_t)sA * 80;
                if (pf) {
                    #pragma unroll
                    for (int q = 0; q < 5; q++) nx[q] = pA[lane + 16 * q];
                }
                float ins = __shfl(iv, t, 16);
                edge_compute(ra, ins);
                if (pf) {
                    #pragma unroll
                    for (int q = 0; q < 5; q++) ra[q] = nx[q];
                }
            }
            // phase B: compute edge t+1 (rb) while loading edge t+3
            if (t + 1 < cnt) {
                uint2 nx[5];
                bool pf = (t + 3) < cnt;
                int sB = __shfl(sv, pf ? t + 3 : 0, 16);
                const uint2* pB = h + (size_t)sB * 80;
                if (pf) {
                    #pragma unroll
                    for (int q = 0; q < 5; q++) nx[q] = pB[lane + 16 * q];
                }
                float ins = __shfl(iv, t + 1, 16);
                edge_compute(rb, ins);
                if (pf) {
                    #pragma unroll
                    for (int q = 0; q < 5; q++) rb[q] = nx[q];
                }
            }
        }
    }
    float inv = 1.f / lrun;
    #pragma unroll
    for (int q = 0; q < 5; q++) { a[q].x *= inv; a[q].y *= inv; a[q].z *= inv; a[q].w *= inv; }

    if (EPI == 0) {
        uint2* po = out_h + (size_t)node * 80;
        #pragma unroll
        for (int q = 0; q < 5; q++) po[lane + 16 * q] = f4_to_h4(a[q]);
        float s2 = 0.f;
        #pragma unroll
        for (int q = 0; q < 5; q++) s2 += dot4(a[q], a[q]);
        #pragma unroll
        for (int m = 8; m >= 1; m >>= 1) s2 += __shfl_xor(s2, m, 16);
        if (lane == 0) inv_out[node] = 1.f / fmaxf(sqrtf(s2), 1e-12f);
    } else {
        const float4* pmw = (const float4*)mw;
        float4 v[5];
        #pragma unroll
        for (int q = 0; q < 5; q++) {
            float4 wq = pmw[lane + 16 * q];
            v[q] = float4{a[q].x * wq.x, a[q].y * wq.y, a[q].z * wq.z, a[q].w * wq.w};
        }
        float4* po = (float4*)(out + (size_t)node * D_BIG);
        #pragma unroll
        for (int q = 0; q < 5; q++) po[lane + 16 * q] = v[q];
        // f: channel c = d & 15; lane L holds d = 4*(L+16q)+e -> c = 4*(L&3)+e.
        float fs0 = v[0].x + v[1].x + v[2].x + v[3].x + v[4].x;
        float fs1 = v[0].y + v[1].y + v[2].y + v[3].y + v[4].y;
        float fs2 = v[0].z + v[1].z + v[2].z + v[3].z + v[4].z;
        float fs3 = v[0].w + v[1].w + v[2].w + v[3].w + v[4].w;
        #pragma unroll
        for (int m = 4; m <= 8; m <<= 1) {
            fs0 += __shfl_xor(fs0, m, 16);
            fs1 += __shfl_xor(fs1, m, 16);
            fs2 += __shfl_xor(fs2, m, 16);
            fs3 += __shfl_xor(fs3, m, 16);
        }
        if (lane < 4)
            ((float4*)(f_out + (size_t)node * 16))[lane] = float4{fs0, fs1, fs2, fs3};
    }
}

// ---------------- fused AGNNConv D=16, 16-lane group per node ----------------
// Depth-2 pipeline. EPI: 0 = store + inv norm; 2 = row softmax(acc*inv_temp).
template <int EPI>
__global__ void agnn_small(const float* __restrict__ h,
                           const unsigned* __restrict__ rowstart,
                           const int* __restrict__ esrc,
                           const int* __restrict__ perm,
                           const float* __restrict__ beta,
                           const float* __restrict__ inv_in,
                           float* __restrict__ out,
                           float* __restrict__ inv_out,       // EPI==0
                           float inv_temp,
                           int n) {
    int g    = (blockIdx.x * blockDim.x + threadIdx.x) >> 4;
    int lane = threadIdx.x & 15;
    if (g >= n) return;
    int node = perm[g];
    unsigned r0 = rowstart[node], r1 = rowstart[node + 1];
    float b0 = beta[0];
    float M  = fabsf(b0);
    float bs = b0 * inv_in[node];

    float dv = h[(size_t)node * 16 + lane];
    float acc = 0.f, lrun = 0.f;

    auto edge_compute = [&](float rv, float ins) {
        float dt = rv * dv;
        #pragma unroll
        for (int m = 8; m >= 1; m >>= 1) dt += __shfl_xor(dt, m, 16);
        float w = __expf(bs * ins * dt - M);
        lrun += w;
        acc += w * rv;
    };

    for (unsigned base = r0; base < r1; base += 16) {
        unsigned j = base + (unsigned)lane;
        bool  vld = j < r1;
        int   sv  = vld ? esrc[j] : 0;
        float iv  = vld ? inv_in[sv] : 0.f;
        int cnt = (int)min(r1 - base, 16u);

        int s0 = __shfl(sv, 0, 16);
        float ra = h[(size_t)s0 * 16 + lane];
        int s1 = __shfl(sv, (cnt > 1) ? 1 : 0, 16);
        float rb = (cnt > 1) ? h[(size_t)s1 * 16 + lane] : 0.f;

        #pragma unroll 1
        for (int t = 0; t < cnt; t += 2) {
            {
                bool pf = (t + 2) < cnt;
                int sA = __shfl(sv, pf ? t + 2 : 0, 16);
                float nx = pf ? h[(size_t)sA * 16 + lane] : 0.f;
                float ins = __shfl(iv, t, 16);
                edge_compute(ra, ins);
                if (pf) ra = nx;
            }
            if (t + 1 < cnt) {
                bool pf = (t + 3) < cnt;
                int sB = __shfl(sv, pf ? t + 3 : 0, 16);
                float nx = pf ? h[(size_t)sB * 16 + lane] : 0.f;
                float ins = __shfl(iv, t + 1, 16);
                edge_compute(rb, ins);
                if (pf) rb = nx;
            }
        }
    }
    float val = acc / lrun;

    if (EPI == 0) {
        out[(size_t)node * 16 + lane] = val;
        float s2 = val * val;
        #pragma unroll
        for (int m = 8; m >= 1; m >>= 1) s2 += __shfl_xor(s2, m, 16);
        if (lane == 0) inv_out[node] = 1.f / fmaxf(sqrtf(s2), 1e-12f);
    } else {
        float v2 = val * inv_temp;
        float mx = v2;
        #pragma unroll
        for (int m = 8; m >= 1; m >>= 1) mx = fmaxf(mx, __shfl_xor(mx, m, 16));
        float ee = __expf(v2 - mx);
        float ss = ee;
        #pragma unroll
        for (int m = 8; m >= 1; m >>= 1) ss += __shfl_xor(ss, m, 16);
        out[(size_t)node * 16 + lane] = ee / ss;
    }
}

// ---------------- BatchNorm stats ----------------
__global__ void bn_reduce(const float* __restrict__ f, float* __restrict__ stats, int n) {
    int c = threadIdx.x & 15;
    int g = threadIdx.x >> 4;
    float s = 0.f, s2 = 0.f;
    for (int i = blockIdx.x * 16 + g; i < n; i += gridDim.x * 16) {
        float v = f[(size_t)i * 16 + c];
        s += v; s2 += v * v;
    }
    __shared__ float ls[256], ls2[256];
    ls[threadIdx.x] = s; ls2[threadIdx.x] = s2;
    __syncthreads();
    for (int off = 128; off >= 16; off >>= 1) {
        if ((int)threadIdx.x < off) {
            ls[threadIdx.x]  += ls[threadIdx.x + off];
            ls2[threadIdx.x] += ls2[threadIdx.x + off];
        }
        __syncthreads();
    }
    if (threadIdx.x < 16) {
        atomicAdd(&stats[threadIdx.x], ls[threadIdx.x]);
        atomicAdd(&stats[16 + threadIdx.x], ls2[threadIdx.x]);
    }
}

// ------- BN finalize+apply + LeakyReLU + softmax(f*10) @ rc + inv-norm(f) ----
// Finalize (mean/var -> scale/shift) recomputed per block from raw stats.
// rc held in 80 per-lane registers (lane L owns columns d = L + 64u, u<5).
__global__ void __launch_bounds__(256)
bn_apply_p(float* __restrict__ f, const float* __restrict__ stats,
           const float* __restrict__ bnw, const float* __restrict__ bnb,
           const float* __restrict__ rc, float* __restrict__ p,
           float* __restrict__ invf, int n) {
    __shared__ float s_sc[16], s_sh[16];
    if (threadIdx.x < 16) {
        int c = threadIdx.x;
        float mean  = stats[c] / (float)n;
        float var   = fmaxf(stats[16 + c] / (float)n - mean * mean, 0.f);
        float scale = bnw[c] / sqrtf(var + 1e-5f);
        s_sc[c] = scale;
        s_sh[c] = bnb[c] - mean * scale;
    }
    __syncthreads();

    int lane = threadIdx.x & 63;

    // per-lane rc fragment: rcw[c][u] = rc[c*320 + lane + 64u] (static idx only)
    float rcw[16][5];
    #pragma unroll
    for (int c = 0; c < 16; c++) {
        #pragma unroll
        for (int u = 0; u < 5; u++) rcw[c][u] = rc[c * D_BIG + lane + 64 * u];
    }

    int wave = (blockIdx.x * blockDim.x + threadIdx.x) >> 6;
    int nw   = (gridDim.x * blockDim.x) >> 6;

    for (int i = wave; i < n; i += nw) {
        const float* fr = f + (size_t)i * 16;
        float fv[16];
        float mx = -1e30f;
        #pragma unroll
        for (int c = 0; c < 16; c++) {
            float v = fmaf(fr[c], s_sc[c], s_sh[c]);
            v = (v >= 0.f) ? v : 0.25f * v;           // LeakyReLU(0.25)
            fv[c] = v;
            mx = fmaxf(mx, v);
        }
        // store-back with static indexing: lanes<16 recompute their own channel
        if (lane < 16) {
            float v = fmaf(fr[lane], s_sc[lane], s_sh[lane]);
            v = (v >= 0.f) ? v : 0.25f * v;
            f[(size_t)i * 16 + lane] = v;
        }

        float s2 = 0.f;
        #pragma unroll
        for (int c = 0; c < 16; c++) s2 += fv[c] * fv[c];
        if (lane == 0) invf[i] = 1.f / fmaxf(sqrtf(s2), 1e-12f);

        float sp[16]; float sum = 0.f;
        #pragma unroll
        for (int c = 0; c < 16; c++) { float t = __expf((fv[c] - mx) * 10.0f); sp[c] = t; sum += t; }
        float isum = 1.f / sum;

        #pragma unroll
        for (int u = 0; u < 5; u++) {
            float acc0 = 0.f, acc1 = 0.f;      // dual partials: shorter dep chain
            #pragma unroll
            for (int c = 0; c < 16; c += 2) {
                acc0 = fmaf(sp[c],     rcw[c][u],     acc0);
                acc1 = fmaf(sp[c + 1], rcw[c + 1][u], acc1);
            }
            p[(size_t)i * D_BIG + lane + 64 * u] = (acc0 + acc1) * isum;
        }
    }
}

extern "C" void kernel_launch(void* const* d_in, const int* in_sizes, int n_in,
                              void* d_out, int out_size, void* d_ws, size_t ws_size,
                              hipStream_t stream) {
    const float* x    = (const float*)d_in[0];
    const int*   src  = (const int*)d_in[1];
    const int*   dst  = (const int*)d_in[2];
    const float* mw   = (const float*)d_in[3];
    const float* bnw  = (const float*)d_in[4];
    const float* bnb  = (const float*)d_in[5];
    const float* rc   = (const float*)d_in[6];
    const float* beta = (const float*)d_in[7];

    const int n  = in_sizes[0] / D_BIG;   // 50000
    const int nE = in_sizes[1];           // 300000

    float* out     = (float*)d_out;
    float* fea_out = out;                          // N*320
    float* f_out   = out + (size_t)n * D_BIG;      // N*16
    float* p_out   = f_out + (size_t)n * 16;       // N*320
    float* o_out   = p_out + (size_t)n * D_BIG;    // N*16

    // fp16 staging parked inside output regions that are dead at that point:
    //   xh  (32MB fp16 x)  -> fea_out region (fea written only by conv2 epilogue)
    //   h1h (32MB fp16 h1) -> p_out region   (p written only by bn_apply_p)
    uint2* xh  = (uint2*)fea_out;
    uint2* h1h = (uint2*)p_out;

    const int TB = 256;
    auto cdiv = [](int a, int b) { return (a + b - 1) / b; };
    const int nb   = cdiv(n, 256);   // 196 (<=256 required by the scans)
    const int ngrp = cdiv(n, 16);    // blocks for 16-lane-group kernels

    // workspace carve (~6.3 MB)
    char* w = (char*)d_ws;
    auto carve = [&](size_t bytes) { void* r = (void*)w; w += (bytes + 255) & ~(size_t)255; return r; };
    unsigned* deg       = (unsigned*)carve((size_t)n * 4);
    unsigned* rowstart  = (unsigned*)carve((size_t)(n + 1) * 4);
    unsigned* cursor    = (unsigned*)carve((size_t)n * 4);
    unsigned* bsum      = (unsigned*)carve(256 * 4);
    int*      esrc      = (int*)carve((size_t)nE * 4);
    float*    stats     = (float*)carve(64 * 4);
    float*    t16       = (float*)carve((size_t)n * 16 * 4);
    int*      perm      = (int*)carve((size_t)n * 4);
    unsigned* blockhist = (unsigned*)carve((size_t)64 * nb * 4);
    unsigned* btot      = (unsigned*)carve(64 * 4);
    float*    inv_x     = (float*)carve((size_t)n * 4);
    float*    inv_h1    = (float*)carve((size_t)n * 4);
    float*    inv_f     = (float*)carve((size_t)n * 4);
    float*    inv_t     = (float*)carve((size_t)n * 4);

    // CSR build + LPT counting sort (14 launches total for the whole net)
    fill_u32<<<cdiv(n, TB), TB, 0, stream>>>(deg, 0u, n);
    count_deg<<<cdiv(nE, TB), TB, 0, stream>>>(dst, deg, nE);
    scan1<<<nb, 256, 0, stream>>>(deg, rowstart, bsum, blockhist, cursor, stats, n, nb);
    scan2b<<<65, 256, 0, stream>>>(bsum, blockhist, btot, nb);
    scan3b<<<nb + 1, 256, 0, stream>>>(rowstart, bsum, btot, n, nE, nb);
    scatter_edges<<<cdiv(nE, TB), TB, 0, stream>>>(src, dst, rowstart, cursor, esrc, nE);
    place2<<<nb, 256, 0, stream>>>(deg, blockhist, btot, perm, n, nb);

    // inv-norm of x + f32->fp16 cast (xh)
    prep_x<<<ngrp, TB, 0, stream>>>(x, xh, inv_x, n);
    // conv1: xh -> h1h (fp16) + inv_h1
    agnn_big<0><<<ngrp, TB, 0, stream>>>(xh, rowstart, esrc, perm, beta, inv_x,
                                         nullptr, nullptr, h1h, inv_h1, nullptr, n);
    // conv2 + marker + f: h1h -> fea_out (f32, overwrites dead xh), f_out
    agnn_big<1><<<ngrp, TB, 0, stream>>>(h1h, rowstart, esrc, perm, beta, inv_h1,
                                         mw, fea_out, nullptr, nullptr, f_out, n);
    // BatchNorm stats (training-mode)
    bn_reduce<<<128, TB, 0, stream>>>(f_out, stats, n);
    // BN finalize+apply + LeakyReLU (f in place) + p = softmax(f*10) @ rc + inv_f
    bn_apply_p<<<1024, TB, 0, stream>>>(f_out, stats, bnw, bnb, rc, p_out, inv_f, n);
    // conv3: f -> t16 + inv_t
    agnn_small<0><<<ngrp, TB, 0, stream>>>(f_out, rowstart, esrc, perm, beta, inv_f,
                                           t16, inv_t, 0.f, n);
    // conv4 + softmax(/T2): t16 -> o_out
    agnn_small<2><<<ngrp, TB, 0, stream>>>(t16, rowstart, esrc, perm, beta, inv_t,
                                           o_out, nullptr, 0.2f, n);
}

// Round 7
// 371.139 us; speedup vs baseline: 1.0413x; 1.0413x over previous
//
#include <hip/hip_runtime.h>
#include <hip/hip_fp16.h>
#include <cstdint>
#include <cstddef>

// GCNClassifier: 2x AGNNConv(D=320) -> marker weight -> BN+LeakyReLU ->
// softmax @ ref_center -> 2x AGNNConv(D=16) -> row softmax.
// N=50000, E=300000 (incl. self-loops => every dst segment non-empty).
//
// R10: consolidation. R9's depth-2 pipeline REGRESSED (+8us: 30 extra VGPR
// + branchy 2-phase body cost more than the extra in-flight row bought ->
// convs are ~15% off the demonstrated random-gather BW ceiling, not
// latency-starved). Convs reverted to R8's depth-1 prefetch verbatim.
// R9's launch diet (17->14 kernels: cursor/stats init folded into scan1,
// scan2+scan_buckets merged, scan_hist folded into scan3, bn_finalize
// folded into bn_apply_p) is kept -- structurally sound, validated.
// Kept from earlier rounds: fp16 gather storage (R7), 16-lane groups +
// hoisted inverse norms + fixed softmax shift M=|beta| (R4/R5),
// LPT descending-degree counting sort (R8), register-resident bn_apply_p (R6).

#define D_BIG 320

__device__ __forceinline__ float dot4(float4 a, float4 b) {
    return a.x * b.x + a.y * b.y + a.z * b.z + a.w * b.w;
}

// fp16 quad <-> float4 (8 bytes per lane-element)
union h4u { uint2 u; __half2 h[2]; };

__device__ __forceinline__ float4 h4_to_f4(uint2 raw) {
    h4u pk; pk.u = raw;
    float2 lo = __half22float2(pk.h[0]);
    float2 hi = __half22float2(pk.h[1]);
    return float4{lo.x, lo.y, hi.x, hi.y};
}

__device__ __forceinline__ uint2 f4_to_h4(float4 v) {
    h4u pk;
    pk.h[0] = __floats2half2_rn(v.x, v.y);
    pk.h[1] = __floats2half2_rn(v.z, v.w);
    return pk.u;
}

__global__ void fill_u32(unsigned* p, unsigned v, int n) {
    int i = blockIdx.x * blockDim.x + threadIdx.x;
    if (i < n) p[i] = v;
}

// ---------------- CSR build (dst-major) ----------------
__global__ void count_deg(const int* __restrict__ dst, unsigned* __restrict__ deg, int nE) {
    int k = blockIdx.x * blockDim.x + threadIdx.x;
    if (k < nE) atomicAdd(&deg[dst[k]], 1u);
}

// Block-local exclusive scan of deg + per-block degree histogram (descending
// bins, LPT) + cursor init + stats zero.
__global__ void scan1(const unsigned* __restrict__ deg, unsigned* __restrict__ rs,
                      unsigned* __restrict__ bsum, unsigned* __restrict__ blockhist,
                      unsigned* __restrict__ cursor, float* __restrict__ stats,
                      int n, int nb) {
    __shared__ unsigned buf[256];
    __shared__ unsigned lh[64];
    if (threadIdx.x < 64) lh[threadIdx.x] = 0u;
    int i = blockIdx.x * 256 + threadIdx.x;
    unsigned v = (i < n) ? deg[i] : 0u;
    buf[threadIdx.x] = v;
    __syncthreads();
    if (i < n) {
        atomicAdd(&lh[63u - min(v, 63u)], 1u);   // LPT: big degrees first
        cursor[i] = 0u;
    }
    if (blockIdx.x == 0 && threadIdx.x < 64) stats[threadIdx.x] = 0.f;
    for (int off = 1; off < 256; off <<= 1) {
        unsigned t = (threadIdx.x >= (unsigned)off) ? buf[threadIdx.x - off] : 0u;
        __syncthreads();
        buf[threadIdx.x] += t;
        __syncthreads();
    }
    if (i < n) rs[i] = buf[threadIdx.x] - v;           // exclusive
    if (threadIdx.x == 255) bsum[blockIdx.x] = buf[255];
    __syncthreads();
    if (threadIdx.x < 64) blockhist[threadIdx.x * nb + blockIdx.x] = lh[threadIdx.x];
}

// Blocks 0..63: per-bucket exclusive scan of blockhist (+ bucket totals).
// Block 64: exclusive scan of bsum. (Independent inputs, both from scan1.)
__global__ void scan2b(unsigned* __restrict__ bsum, unsigned* __restrict__ blockhist,
                       unsigned* __restrict__ btot, int nb) {
    __shared__ unsigned buf[256];
    int k = threadIdx.x;
    if (blockIdx.x == 64) {
        unsigned v = (k < nb) ? bsum[k] : 0u;
        buf[k] = v;
        __syncthreads();
        for (int off = 1; off < 256; off <<= 1) {
            unsigned t = (k >= off) ? buf[k - off] : 0u;
            __syncthreads();
            buf[k] += t;
            __syncthreads();
        }
        if (k < nb) bsum[k] = buf[k] - v;             // exclusive
    } else {
        int b = blockIdx.x;                           // bucket
        unsigned v = (k < nb) ? blockhist[b * nb + k] : 0u;
        buf[k] = v;
        __syncthreads();
        for (int off = 1; off < 256; off <<= 1) {
            unsigned t = (k >= off) ? buf[k - off] : 0u;
            __syncthreads();
            buf[k] += t;
            __syncthreads();
        }
        if (k < nb) blockhist[b * nb + k] = buf[k] - v;   // exclusive within bucket
        if (k == 255) btot[b] = buf[255];                 // bucket total
    }
}

// Blocks 0..nb-1: finalize rowstart. Block nb: exclusive scan of btot -> bases.
__global__ void scan3b(unsigned* __restrict__ rs, const unsigned* __restrict__ bsum,
                       unsigned* __restrict__ btot, int n, int nE, int nb) {
    if ((int)blockIdx.x == nb) {
        if (threadIdx.x < 64) {
            int t = threadIdx.x;
            unsigned v = btot[t];
            unsigned p = v;
            #pragma unroll
            for (int off = 1; off < 64; off <<= 1) {
                unsigned o = __shfl_up(p, off, 64);
                if (t >= off) p += o;
            }
            btot[t] = p - v;   // exclusive
        }
        return;
    }
    int i = blockIdx.x * 256 + threadIdx.x;
    if (i < n) rs[i] += bsum[blockIdx.x];
    if (i == 0) rs[n] = (unsigned)nE;
}

__global__ void scatter_edges(const int* __restrict__ src, const int* __restrict__ dst,
                              const unsigned* __restrict__ rowstart, unsigned* __restrict__ cursor,
                              int* __restrict__ esrc, int nE) {
    int k = blockIdx.x * blockDim.x + threadIdx.x;
    if (k >= nE) return;
    int t = dst[k];
    unsigned pos = rowstart[t] + atomicAdd(&cursor[t], 1u);
    esrc[pos] = src[k];
}

__global__ void place2(const unsigned* __restrict__ deg, const unsigned* __restrict__ blockhist,
                       const unsigned* __restrict__ bbase, int* __restrict__ perm,
                       int n, int nb) {
    __shared__ unsigned lc[64];
    if (threadIdx.x < 64) lc[threadIdx.x] = 0u;
    __syncthreads();
    int i = blockIdx.x * 256 + threadIdx.x;
    if (i < n) {
        unsigned bin  = 63u - min(deg[i], 63u);       // LPT: descending degree
        unsigned rank = atomicAdd(&lc[bin], 1u);
        unsigned pos  = bbase[bin] + blockhist[bin * nb + blockIdx.x] + rank;
        perm[pos] = i;
    }
}

// -------- prep: inverse L2 norm of x rows + f32 -> fp16 cast --------
__global__ void prep_x(const float* __restrict__ x, uint2* __restrict__ xh,
                       float* __restrict__ invn, int n) {
    int g    = (blockIdx.x * blockDim.x + threadIdx.x) >> 4;
    int lane = threadIdx.x & 15;
    if (g >= n) return;
    const float4* p = (const float4*)(x + (size_t)g * D_BIG);
    uint2* ph = xh + (size_t)g * 80;          // 320 halves = 80 uint2
    float s2 = 0.f;
    #pragma unroll
    for (int q = 0; q < 5; q++) {
        float4 v = p[lane + 16 * q];
        s2 += dot4(v, v);
        ph[lane + 16 * q] = f4_to_h4(v);
    }
    #pragma unroll
    for (int m = 8; m >= 1; m >>= 1) s2 += __shfl_xor(s2, m, 16);
    if (lane == 0) invn[g] = 1.f / fmaxf(sqrtf(s2), 1e-12f);
}

// ---------------- fused AGNNConv D=320, 16-lane group per node ----------------
// fp16 rows (80 uint2/row); depth-1 software prefetch (R8, proven).
// EPI: 0 = write fp16 aggregate + its inverse norm; 1 = f32 marker-weight + f
template <int EPI>
__global__ void agnn_big(const uint2* __restrict__ h,     // fp16 rows
                         const unsigned* __restrict__ rowstart,
                         const int* __restrict__ esrc,
                         const int* __restrict__ perm,
                         const float* __restrict__ beta,
                         const float* __restrict__ inv_in,
                         const float* __restrict__ mw,    // EPI==1
                         float* __restrict__ out,         // EPI==1 (f32 fea)
                         uint2* __restrict__ out_h,       // EPI==0 (fp16 h1)
                         float* __restrict__ inv_out,     // EPI==0
                         float* __restrict__ f_out,       // EPI==1
                         int n) {
    int g    = (blockIdx.x * blockDim.x + threadIdx.x) >> 4;
    int lane = threadIdx.x & 15;
    if (g >= n) return;
    int node = perm[g];
    unsigned r0 = rowstart[node], r1 = rowstart[node + 1];
    float b0 = beta[0];
    float M  = fabsf(b0);            // |score| <= |b0| (cosine in [-1,1], temp=1)
    float bs = b0 * inv_in[node];    // score = bs * inv_n[src] * (h_s . h_d)

    const uint2* pd = h + (size_t)node * 80;
    float4 d[5];
    #pragma unroll
    for (int q = 0; q < 5; q++) d[q] = h4_to_f4(pd[lane + 16 * q]);

    float4 a[5];
    #pragma unroll
    for (int q = 0; q < 5; q++) a[q] = float4{0.f, 0.f, 0.f, 0.f};
    float lrun = 0.f;

    for (unsigned base = r0; base < r1; base += 16) {
        unsigned j = base + (unsigned)lane;
        bool  vld = j < r1;
        int   sv  = vld ? esrc[j] : 0;
        float iv  = vld ? inv_in[sv] : 0.f;
        int cnt = (int)min(r1 - base, 16u);
        // prefetch edge 0 of this chunk
        int s0 = __shfl(sv, 0, 16);
        const uint2* ps0 = h + (size_t)s0 * 80;
        uint2 rn[5];
        #pragma unroll
        for (int q = 0; q < 5; q++) rn[q] = ps0[lane + 16 * q];

        for (int t = 0; t < cnt; t++) {
            uint2 rcur[5];
            #pragma unroll
            for (int q = 0; q < 5; q++) rcur[q] = rn[q];
            if (t + 1 < cnt) {                      // issue next edge's loads now
                int s1 = __shfl(sv, t + 1, 16);
                const uint2* ps1 = h + (size_t)s1 * 80;
                #pragma unroll
                for (int q = 0; q < 5; q++) rn[q] = ps1[lane + 16 * q];
            }
            float ins = __shfl(iv, t, 16);
            float4 r[5];
            #pragma unroll
            for (int q = 0; q < 5; q++) r[q] = h4_to_f4(rcur[q]);
            float dt = 0.f;
            #pragma unroll
            for (int q = 0; q < 5; q++) dt += dot4(r[q], d[q]);
            #pragma unroll
            for (int m = 8; m >= 1; m >>= 1) dt += __shfl_xor(dt, m, 16);
            float w = __expf(bs * ins * dt - M);
            lrun += w;
            #pragma unroll
            for (int q = 0; q < 5; q++) {
                a[q].x += w * r[q].x; a[q].y += w * r[q].y;
                a[q].z += w * r[q].z; a[q].w += w * r[q].w;
            }
        }
    }
    float inv = 1.f / lrun;
    #pragma unroll
    for (int q = 0; q < 5; q++) { a[q].x *= inv; a[q].y *= inv; a[q].z *= inv; a[q].w *= inv; }

    if (EPI == 0) {
        uint2* po = out_h + (size_t)node * 80;
        #pragma unroll
        for (int q = 0; q < 5; q++) po[lane + 16 * q] = f4_to_h4(a[q]);
        float s2 = 0.f;
        #pragma unroll
        for (int q = 0; q < 5; q++) s2 += dot4(a[q], a[q]);
        #pragma unroll
        for (int m = 8; m >= 1; m >>= 1) s2 += __shfl_xor(s2, m, 16);
        if (lane == 0) inv_out[node] = 1.f / fmaxf(sqrtf(s2), 1e-12f);
    } else {
        const float4* pmw = (const float4*)mw;
        float4 v[5];
        #pragma unroll
        for (int q = 0; q < 5; q++) {
            float4 wq = pmw[lane + 16 * q];
            v[q] = float4{a[q].x * wq.x, a[q].y * wq.y, a[q].z * wq.z, a[q].w * wq.w};
        }
        float4* po = (float4*)(out + (size_t)node * D_BIG);
        #pragma unroll
        for (int q = 0; q < 5; q++) po[lane + 16 * q] = v[q];
        // f: channel c = d & 15; lane L holds d = 4*(L+16q)+e -> c = 4*(L&3)+e.
        float fs0 = v[0].x + v[1].x + v[2].x + v[3].x + v[4].x;
        float fs1 = v[0].y + v[1].y + v[2].y + v[3].y + v[4].y;
        float fs2 = v[0].z + v[1].z + v[2].z + v[3].z + v[4].z;
        float fs3 = v[0].w + v[1].w + v[2].w + v[3].w + v[4].w;
        #pragma unroll
        for (int m = 4; m <= 8; m <<= 1) {
            fs0 += __shfl_xor(fs0, m, 16);
            fs1 += __shfl_xor(fs1, m, 16);
            fs2 += __shfl_xor(fs2, m, 16);
            fs3 += __shfl_xor(fs3, m, 16);
        }
        if (lane < 4)
            ((float4*)(f_out + (size_t)node * 16))[lane] = float4{fs0, fs1, fs2, fs3};
    }
}

// ---------------- fused AGNNConv D=16, 16-lane group per node ----------------
// Depth-1 software prefetch (R8). EPI: 0 = store + inv norm; 2 = row softmax.
template <int EPI>
__global__ void agnn_small(const float* __restrict__ h,
                           const unsigned* __restrict__ rowstart,
                           const int* __restrict__ esrc,
                           const int* __restrict__ perm,
                           const float* __restrict__ beta,
                           const float* __restrict__ inv_in,
                           float* __restrict__ out,
                           float* __restrict__ inv_out,       // EPI==0
                           float inv_temp,
                           int n) {
    int g    = (blockIdx.x * blockDim.x + threadIdx.x) >> 4;
    int lane = threadIdx.x & 15;
    if (g >= n) return;
    int node = perm[g];
    unsigned r0 = rowstart[node], r1 = rowstart[node + 1];
    float b0 = beta[0];
    float M  = fabsf(b0);
    float bs = b0 * inv_in[node];

    float dv = h[(size_t)node * 16 + lane];
    float acc = 0.f, lrun = 0.f;

    for (unsigned base = r0; base < r1; base += 16) {
        unsigned j = base + (unsigned)lane;
        bool  vld = j < r1;
        int   sv  = vld ? esrc[j] : 0;
        float iv  = vld ? inv_in[sv] : 0.f;
        int cnt = (int)min(r1 - base, 16u);
        int s0 = __shfl(sv, 0, 16);
        float rv_next = h[(size_t)s0 * 16 + lane];
        for (int t = 0; t < cnt; t++) {
            float rv = rv_next;
            if (t + 1 < cnt) {
                int s1 = __shfl(sv, t + 1, 16);
                rv_next = h[(size_t)s1 * 16 + lane];
            }
            float ins = __shfl(iv, t, 16);
            float dt = rv * dv;
            #pragma unroll
            for (int m = 8; m >= 1; m >>= 1) dt += __shfl_xor(dt, m, 16);
            float w = __expf(bs * ins * dt - M);
            lrun += w;
            acc += w * rv;
        }
    }
    float val = acc / lrun;

    if (EPI == 0) {
        out[(size_t)node * 16 + lane] = val;
        float s2 = val * val;
        #pragma unroll
        for (int m = 8; m >= 1; m >>= 1) s2 += __shfl_xor(s2, m, 16);
        if (lane == 0) inv_out[node] = 1.f / fmaxf(sqrtf(s2), 1e-12f);
    } else {
        float v2 = val * inv_temp;
        float mx = v2;
        #pragma unroll
        for (int m = 8; m >= 1; m >>= 1) mx = fmaxf(mx, __shfl_xor(mx, m, 16));
        float ee = __expf(v2 - mx);
        float ss = ee;
        #pragma unroll
        for (int m = 8; m >= 1; m >>= 1) ss += __shfl_xor(ss, m, 16);
        out[(size_t)node * 16 + lane] = ee / ss;
    }
}

// ---------------- BatchNorm stats ----------------
__global__ void bn_reduce(const float* __restrict__ f, float* __restrict__ stats, int n) {
    int c = threadIdx.x & 15;
    int g = threadIdx.x >> 4;
    float s = 0.f, s2 = 0.f;
    for (int i = blockIdx.x * 16 + g; i < n; i += gridDim.x * 16) {
        float v = f[(size_t)i * 16 + c];
        s += v; s2 += v * v;
    }
    __shared__ float ls[256], ls2[256];
    ls[threadIdx.x] = s; ls2[threadIdx.x] = s2;
    __syncthreads();
    for (int off = 128; off >= 16; off >>= 1) {
        if ((int)threadIdx.x < off) {
            ls[threadIdx.x]  += ls[threadIdx.x + off];
            ls2[threadIdx.x] += ls2[threadIdx.x + off];
        }
        __syncthreads();
    }
    if (threadIdx.x < 16) {
        atomicAdd(&stats[threadIdx.x], ls[threadIdx.x]);
        atomicAdd(&stats[16 + threadIdx.x], ls2[threadIdx.x]);
    }
}

// ------- BN finalize+apply + LeakyReLU + softmax(f*10) @ rc + inv-norm(f) ----
// Finalize (mean/var -> scale/shift) recomputed per block from raw stats.
// rc held in 80 per-lane registers (lane L owns columns d = L + 64u, u<5).
__global__ void __launch_bounds__(256)
bn_apply_p(float* __restrict__ f, const float* __restrict__ stats,
           const float* __restrict__ bnw, const float* __restrict__ bnb,
           const float* __restrict__ rc, float* __restrict__ p,
           float* __restrict__ invf, int n) {
    __shared__ float s_sc[16], s_sh[16];
    if (threadIdx.x < 16) {
        int c = threadIdx.x;
        float mean  = stats[c] / (float)n;
        float var   = fmaxf(stats[16 + c] / (float)n - mean * mean, 0.f);
        float scale = bnw[c] / sqrtf(var + 1e-5f);
        s_sc[c] = scale;
        s_sh[c] = bnb[c] - mean * scale;
    }
    __syncthreads();

    int lane = threadIdx.x & 63;

    // per-lane rc fragment: rcw[c][u] = rc[c*320 + lane + 64u] (static idx only)
    float rcw[16][5];
    #pragma unroll
    for (int c = 0; c < 16; c++) {
        #pragma unroll
        for (int u = 0; u < 5; u++) rcw[c][u] = rc[c * D_BIG + lane + 64 * u];
    }

    int wave = (blockIdx.x * blockDim.x + threadIdx.x) >> 6;
    int nw   = (gridDim.x * blockDim.x) >> 6;

    for (int i = wave; i < n; i += nw) {
        const float* fr = f + (size_t)i * 16;
        float fv[16];
        float mx = -1e30f;
        #pragma unroll
        for (int c = 0; c < 16; c++) {
            float v = fmaf(fr[c], s_sc[c], s_sh[c]);
            v = (v >= 0.f) ? v : 0.25f * v;           // LeakyReLU(0.25)
            fv[c] = v;
            mx = fmaxf(mx, v);
        }
        // store-back with static indexing: lanes<16 recompute their own channel
        if (lane < 16) {
            float v = fmaf(fr[lane], s_sc[lane], s_sh[lane]);
            v = (v >= 0.f) ? v : 0.25f * v;
            f[(size_t)i * 16 + lane] = v;
        }

        float s2 = 0.f;
        #pragma unroll
        for (int c = 0; c < 16; c++) s2 += fv[c] * fv[c];
        if (lane == 0) invf[i] = 1.f / fmaxf(sqrtf(s2), 1e-12f);

        float sp[16]; float sum = 0.f;
        #pragma unroll
        for (int c = 0; c < 16; c++) { float t = __expf((fv[c] - mx) * 10.0f); sp[c] = t; sum += t; }
        float isum = 1.f / sum;

        #pragma unroll
        for (int u = 0; u < 5; u++) {
            float acc0 = 0.f, acc1 = 0.f;      // dual partials: shorter dep chain
            #pragma unroll
            for (int c = 0; c < 16; c += 2) {
                acc0 = fmaf(sp[c],     rcw[c][u],     acc0);
                acc1 = fmaf(sp[c + 1], rcw[c + 1][u], acc1);
            }
            p[(size_t)i * D_BIG + lane + 64 * u] = (acc0 + acc1) * isum;
        }
    }
}

extern "C" void kernel_launch(void* const* d_in, const int* in_sizes, int n_in,
                              void* d_out, int out_size, void* d_ws, size_t ws_size,
                              hipStream_t stream) {
    const float* x    = (const float*)d_in[0];
    const int*   src  = (const int*)d_in[1];
    const int*   dst  = (const int*)d_in[2];
    const float* mw   = (const float*)d_in[3];
    const float* bnw  = (const float*)d_in[4];
    const float* bnb  = (const float*)d_in[5];
    const float* rc   = (const float*)d_in[6];
    const float* beta = (const float*)d_in[7];

    const int n  = in_sizes[0] / D_BIG;   // 50000
    const int nE = in_sizes[1];           // 300000

    float* out     = (float*)d_out;
    float* fea_out = out;                          // N*320
    float* f_out   = out + (size_t)n * D_BIG;      // N*16
    float* p_out   = f_out + (size_t)n * 16;       // N*320
    float* o_out   = p_out + (size_t)n * D_BIG;    // N*16

    // fp16 staging parked inside output regions that are dead at that point:
    //   xh  (32MB fp16 x)  -> fea_out region (fea written only by conv2 epilogue)
    //   h1h (32MB fp16 h1) -> p_out region   (p written only by bn_apply_p)
    uint2* xh  = (uint2*)fea_out;
    uint2* h1h = (uint2*)p_out;

    const int TB = 256;
    auto cdiv = [](int a, int b) { return (a + b - 1) / b; };
    const int nb   = cdiv(n, 256);   // 196 (<=256 required by the scans)
    const int ngrp = cdiv(n, 16);    // blocks for 16-lane-group kernels

    // workspace carve (~6.3 MB)
    char* w = (char*)d_ws;
    auto carve = [&](size_t bytes) { void* r = (void*)w; w += (bytes + 255) & ~(size_t)255; return r; };
    unsigned* deg       = (unsigned*)carve((size_t)n * 4);
    unsigned* rowstart  = (unsigned*)carve((size_t)(n + 1) * 4);
    unsigned* cursor    = (unsigned*)carve((size_t)n * 4);
    unsigned* bsum      = (unsigned*)carve(256 * 4);
    int*      esrc      = (int*)carve((size_t)nE * 4);
    float*    stats     = (float*)carve(64 * 4);
    float*    t16       = (float*)carve((size_t)n * 16 * 4);
    int*      perm      = (int*)carve((size_t)n * 4);
    unsigned* blockhist = (unsigned*)carve((size_t)64 * nb * 4);
    unsigned* btot      = (unsigned*)carve(64 * 4);
    float*    inv_x     = (float*)carve((size_t)n * 4);
    float*    inv_h1    = (float*)carve((size_t)n * 4);
    float*    inv_f     = (float*)carve((size_t)n * 4);
    float*    inv_t     = (float*)carve((size_t)n * 4);

    // CSR build + LPT counting sort (14 launches total for the whole net)
    fill_u32<<<cdiv(n, TB), TB, 0, stream>>>(deg, 0u, n);
    count_deg<<<cdiv(nE, TB), TB, 0, stream>>>(dst, deg, nE);
    scan1<<<nb, 256, 0, stream>>>(deg, rowstart, bsum, blockhist, cursor, stats, n, nb);
    scan2b<<<65, 256, 0, stream>>>(bsum, blockhist, btot, nb);
    scan3b<<<nb + 1, 256, 0, stream>>>(rowstart, bsum, btot, n, nE, nb);
    scatter_edges<<<cdiv(nE, TB), TB, 0, stream>>>(src, dst, rowstart, cursor, esrc, nE);
    place2<<<nb, 256, 0, stream>>>(deg, blockhist, btot, perm, n, nb);

    // inv-norm of x + f32->fp16 cast (xh)
    prep_x<<<ngrp, TB, 0, stream>>>(x, xh, inv_x, n);
    // conv1: xh -> h1h (fp16) + inv_h1
    agnn_big<0><<<ngrp, TB, 0, stream>>>(xh, rowstart, esrc, perm, beta, inv_x,
                                         nullptr, nullptr, h1h, inv_h1, nullptr, n);
    // conv2 + marker + f: h1h -> fea_out (f32, overwrites dead xh), f_out
    agnn_big<1><<<ngrp, TB, 0, stream>>>(h1h, rowstart, esrc, perm, beta, inv_h1,
                                         mw, fea_out, nullptr, nullptr, f_out, n);
    // BatchNorm stats (training-mode)
    bn_reduce<<<128, TB, 0, stream>>>(f_out, stats, n);
    // BN finalize+apply + LeakyReLU (f in place) + p = softmax(f*10) @ rc + inv_f
    bn_apply_p<<<1024, TB, 0, stream>>>(f_out, stats, bnw, bnb, rc, p_out, inv_f, n);
    // conv3: f -> t16 + inv_t
    agnn_small<0><<<ngrp, TB, 0, stream>>>(f_out, rowstart, esrc, perm, beta, inv_f,
                                           t16, inv_t, 0.f, n);
    // conv4 + softmax(/T2): t16 -> o_out
    agnn_small<2><<<ngrp, TB, 0, stream>>>(t16, rowstart, esrc, perm, beta, inv_t,
                                           o_out, nullptr, 0.2f, n);
}

// Round 8
// 368.232 us; speedup vs baseline: 1.0495x; 1.0079x over previous
//
#include <hip/hip_runtime.h>
#include <hip/hip_fp16.h>
#include <cstdint>
#include <cstddef>

// GCNClassifier: 2x AGNNConv(D=320) -> marker weight -> BN+LeakyReLU ->
// softmax @ ref_center -> 2x AGNNConv(D=16) -> row softmax.
// N=50000, E=300000 (incl. self-loops => every dst segment non-empty).
//
// R11 (on top of R10):
//  - self-loop skip in all 4 convs: for edges with src==node the row is the
//    dst row already unpacked in registers (same fp16 source -> bitwise
//    identical); skip the 640B (resp. 64B) gather. 50K/300K edges = 1/6 of
//    gather work removed, math unchanged to the bit.
//  - place2 merged into scatter_edges (one launch, block-range split);
//    13 launches total.
// Kept: fp16 gather storage (R7), depth-1 prefetch (R8), 16-lane groups +
// hoisted inverse norms + fixed softmax shift (R4/R5), LPT sort (R8),
// launch diet (R9), register-resident bn_apply_p (R6).

#define D_BIG 320

__device__ __forceinline__ float dot4(float4 a, float4 b) {
    return a.x * b.x + a.y * b.y + a.z * b.z + a.w * b.w;
}

// fp16 quad <-> float4 (8 bytes per lane-element)
union h4u { uint2 u; __half2 h[2]; };

__device__ __forceinline__ float4 h4_to_f4(uint2 raw) {
    h4u pk; pk.u = raw;
    float2 lo = __half22float2(pk.h[0]);
    float2 hi = __half22float2(pk.h[1]);
    return float4{lo.x, lo.y, hi.x, hi.y};
}

__device__ __forceinline__ uint2 f4_to_h4(float4 v) {
    h4u pk;
    pk.h[0] = __floats2half2_rn(v.x, v.y);
    pk.h[1] = __floats2half2_rn(v.z, v.w);
    return pk.u;
}

__global__ void fill_u32(unsigned* p, unsigned v, int n) {
    int i = blockIdx.x * blockDim.x + threadIdx.x;
    if (i < n) p[i] = v;
}

// ---------------- CSR build (dst-major) ----------------
__global__ void count_deg(const int* __restrict__ dst, unsigned* __restrict__ deg, int nE) {
    int k = blockIdx.x * blockDim.x + threadIdx.x;
    if (k < nE) atomicAdd(&deg[dst[k]], 1u);
}

// Block-local exclusive scan of deg + per-block degree histogram (descending
// bins, LPT) + cursor init + stats zero.
__global__ void scan1(const unsigned* __restrict__ deg, unsigned* __restrict__ rs,
                      unsigned* __restrict__ bsum, unsigned* __restrict__ blockhist,
                      unsigned* __restrict__ cursor, float* __restrict__ stats,
                      int n, int nb) {
    __shared__ unsigned buf[256];
    __shared__ unsigned lh[64];
    if (threadIdx.x < 64) lh[threadIdx.x] = 0u;
    int i = blockIdx.x * 256 + threadIdx.x;
    unsigned v = (i < n) ? deg[i] : 0u;
    buf[threadIdx.x] = v;
    __syncthreads();
    if (i < n) {
        atomicAdd(&lh[63u - min(v, 63u)], 1u);   // LPT: big degrees first
        cursor[i] = 0u;
    }
    if (blockIdx.x == 0 && threadIdx.x < 64) stats[threadIdx.x] = 0.f;
    for (int off = 1; off < 256; off <<= 1) {
        unsigned t = (threadIdx.x >= (unsigned)off) ? buf[threadIdx.x - off] : 0u;
        __syncthreads();
        buf[threadIdx.x] += t;
        __syncthreads();
    }
    if (i < n) rs[i] = buf[threadIdx.x] - v;           // exclusive
    if (threadIdx.x == 255) bsum[blockIdx.x] = buf[255];
    __syncthreads();
    if (threadIdx.x < 64) blockhist[threadIdx.x * nb + blockIdx.x] = lh[threadIdx.x];
}

// Blocks 0..63: per-bucket exclusive scan of blockhist (+ bucket totals).
// Block 64: exclusive scan of bsum. (Independent inputs, both from scan1.)
__global__ void scan2b(unsigned* __restrict__ bsum, unsigned* __restrict__ blockhist,
                       unsigned* __restrict__ btot, int nb) {
    __shared__ unsigned buf[256];
    int k = threadIdx.x;
    if (blockIdx.x == 64) {
        unsigned v = (k < nb) ? bsum[k] : 0u;
        buf[k] = v;
        __syncthreads();
        for (int off = 1; off < 256; off <<= 1) {
            unsigned t = (k >= off) ? buf[k - off] : 0u;
            __syncthreads();
            buf[k] += t;
            __syncthreads();
        }
        if (k < nb) bsum[k] = buf[k] - v;             // exclusive
    } else {
        int b = blockIdx.x;                           // bucket
        unsigned v = (k < nb) ? blockhist[b * nb + k] : 0u;
        buf[k] = v;
        __syncthreads();
        for (int off = 1; off < 256; off <<= 1) {
            unsigned t = (k >= off) ? buf[k - off] : 0u;
            __syncthreads();
            buf[k] += t;
            __syncthreads();
        }
        if (k < nb) blockhist[b * nb + k] = buf[k] - v;   // exclusive within bucket
        if (k == 255) btot[b] = buf[255];                 // bucket total
    }
}

// Blocks 0..nb-1: finalize rowstart. Block nb: exclusive scan of btot -> bases.
__global__ void scan3b(unsigned* __restrict__ rs, const unsigned* __restrict__ bsum,
                       unsigned* __restrict__ btot, int n, int nE, int nb) {
    if ((int)blockIdx.x == nb) {
        if (threadIdx.x < 64) {
            int t = threadIdx.x;
            unsigned v = btot[t];
            unsigned p = v;
            #pragma unroll
            for (int off = 1; off < 64; off <<= 1) {
                unsigned o = __shfl_up(p, off, 64);
                if (t >= off) p += o;
            }
            btot[t] = p - v;   // exclusive
        }
        return;
    }
    int i = blockIdx.x * 256 + threadIdx.x;
    if (i < n) rs[i] += bsum[blockIdx.x];
    if (i == 0) rs[n] = (unsigned)nE;
}

// Blocks 0..nbE-1: scatter edges into CSR. Blocks nbE..nbE+nb-1: place nodes
// into perm (LPT order). Both depend only on scan2b/scan3b outputs.
__global__ void scatter_place(const int* __restrict__ src, const int* __restrict__ dst,
                              const unsigned* __restrict__ rowstart, unsigned* __restrict__ cursor,
                              int* __restrict__ esrc,
                              const unsigned* __restrict__ deg,
                              const unsigned* __restrict__ blockhist,
                              const unsigned* __restrict__ bbase, int* __restrict__ perm,
                              int nE, int n, int nb, int nbE) {
    __shared__ unsigned lc[64];
    if ((int)blockIdx.x < nbE) {
        int k = blockIdx.x * 256 + threadIdx.x;
        if (k < nE) {
            int t = dst[k];
            unsigned pos = rowstart[t] + atomicAdd(&cursor[t], 1u);
            esrc[pos] = src[k];
        }
    } else {
        int b = blockIdx.x - nbE;
        if (threadIdx.x < 64) lc[threadIdx.x] = 0u;
        __syncthreads();
        int i = b * 256 + threadIdx.x;
        if (i < n) {
            unsigned bin  = 63u - min(deg[i], 63u);   // LPT: descending degree
            unsigned rank = atomicAdd(&lc[bin], 1u);
            unsigned pos  = bbase[bin] + blockhist[bin * nb + b] + rank;
            perm[pos] = i;
        }
    }
}

// -------- prep: inverse L2 norm of x rows + f32 -> fp16 cast --------
__global__ void prep_x(const float* __restrict__ x, uint2* __restrict__ xh,
                       float* __restrict__ invn, int n) {
    int g    = (blockIdx.x * blockDim.x + threadIdx.x) >> 4;
    int lane = threadIdx.x & 15;
    if (g >= n) return;
    const float4* p = (const float4*)(x + (size_t)g * D_BIG);
    uint2* ph = xh + (size_t)g * 80;          // 320 halves = 80 uint2
    float s2 = 0.f;
    #pragma unroll
    for (int q = 0; q < 5; q++) {
        float4 v = p[lane + 16 * q];
        s2 += dot4(v, v);
        ph[lane + 16 * q] = f4_to_h4(v);
    }
    #pragma unroll
    for (int m = 8; m >= 1; m >>= 1) s2 += __shfl_xor(s2, m, 16);
    if (lane == 0) invn[g] = 1.f / fmaxf(sqrtf(s2), 1e-12f);
}

// ---------------- fused AGNNConv D=320, 16-lane group per node ----------------
// fp16 rows (80 uint2/row); depth-1 prefetch; self-loop edges reuse the dst
// row already in registers (no gather).
// EPI: 0 = write fp16 aggregate + its inverse norm; 1 = f32 marker-weight + f
template <int EPI>
__global__ void agnn_big(const uint2* __restrict__ h,     // fp16 rows
                         const unsigned* __restrict__ rowstart,
                         const int* __restrict__ esrc,
                         const int* __restrict__ perm,
                         const float* __restrict__ beta,
                         const float* __restrict__ inv_in,
                         const float* __restrict__ mw,    // EPI==1
                         float* __restrict__ out,         // EPI==1 (f32 fea)
                         uint2* __restrict__ out_h,       // EPI==0 (fp16 h1)
                         float* __restrict__ inv_out,     // EPI==0
                         float* __restrict__ f_out,       // EPI==1
                         int n) {
    int g    = (blockIdx.x * blockDim.x + threadIdx.x) >> 4;
    int lane = threadIdx.x & 15;
    if (g >= n) return;
    int node = perm[g];
    unsigned r0 = rowstart[node], r1 = rowstart[node + 1];
    float b0 = beta[0];
    float M  = fabsf(b0);            // |score| <= |b0| (cosine in [-1,1], temp=1)
    float bs = b0 * inv_in[node];    // score = bs * inv_n[src] * (h_s . h_d)

    const uint2* pd = h + (size_t)node * 80;
    float4 d[5];
    #pragma unroll
    for (int q = 0; q < 5; q++) d[q] = h4_to_f4(pd[lane + 16 * q]);

    float4 a[5];
    #pragma unroll
    for (int q = 0; q < 5; q++) a[q] = float4{0.f, 0.f, 0.f, 0.f};
    float lrun = 0.f;

    for (unsigned base = r0; base < r1; base += 16) {
        unsigned j = base + (unsigned)lane;
        bool  vld = j < r1;
        int   sv  = vld ? esrc[j] : 0;
        float iv  = vld ? inv_in[sv] : 0.f;
        int cnt = (int)min(r1 - base, 16u);

        uint2 rn[5] = {};
        int s0 = __shfl(sv, 0, 16);
        bool nself = (s0 == node);             // self-loop: row == d[], skip gather
        if (!nself) {
            const uint2* ps0 = h + (size_t)s0 * 80;
            #pragma unroll
            for (int q = 0; q < 5; q++) rn[q] = ps0[lane + 16 * q];
        }

        for (int t = 0; t < cnt; t++) {
            bool cself = nself;
            uint2 rcur[5];
            #pragma unroll
            for (int q = 0; q < 5; q++) rcur[q] = rn[q];
            if (t + 1 < cnt) {                      // issue next edge's loads now
                int s1 = __shfl(sv, t + 1, 16);
                nself = (s1 == node);
                if (!nself) {
                    const uint2* ps1 = h + (size_t)s1 * 80;
                    #pragma unroll
                    for (int q = 0; q < 5; q++) rn[q] = ps1[lane + 16 * q];
                }
            }
            float ins = __shfl(iv, t, 16);
            float4 r[5];
            #pragma unroll
            for (int q = 0; q < 5; q++) r[q] = cself ? d[q] : h4_to_f4(rcur[q]);
            float dt = 0.f;
            #pragma unroll
            for (int q = 0; q < 5; q++) dt += dot4(r[q], d[q]);
            #pragma unroll
            for (int m = 8; m >= 1; m >>= 1) dt += __shfl_xor(dt, m, 16);
            float w = __expf(bs * ins * dt - M);
            lrun += w;
            #pragma unroll
            for (int q = 0; q < 5; q++) {
                a[q].x += w * r[q].x; a[q].y += w * r[q].y;
                a[q].z += w * r[q].z; a[q].w += w * r[q].w;
            }
        }
    }
    float inv = 1.f / lrun;
    #pragma unroll
    for (int q = 0; q < 5; q++) { a[q].x *= inv; a[q].y *= inv; a[q].z *= inv; a[q].w *= inv; }

    if (EPI == 0) {
        uint2* po = out_h + (size_t)node * 80;
        #pragma unroll
        for (int q = 0; q < 5; q++) po[lane + 16 * q] = f4_to_h4(a[q]);
        float s2 = 0.f;
        #pragma unroll
        for (int q = 0; q < 5; q++) s2 += dot4(a[q], a[q]);
        #pragma unroll
        for (int m = 8; m >= 1; m >>= 1) s2 += __shfl_xor(s2, m, 16);
        if (lane == 0) inv_out[node] = 1.f / fmaxf(sqrtf(s2), 1e-12f);
    } else {
        const float4* pmw = (const float4*)mw;
        float4 v[5];
        #pragma unroll
        for (int q = 0; q < 5; q++) {
            float4 wq = pmw[lane + 16 * q];
            v[q] = float4{a[q].x * wq.x, a[q].y * wq.y, a[q].z * wq.z, a[q].w * wq.w};
        }
        float4* po = (float4*)(out + (size_t)node * D_BIG);
        #pragma unroll
        for (int q = 0; q < 5; q++) po[lane + 16 * q] = v[q];
        // f: channel c = d & 15; lane L holds d = 4*(L+16q)+e -> c = 4*(L&3)+e.
        float fs0 = v[0].x + v[1].x + v[2].x + v[3].x + v[4].x;
        float fs1 = v[0].y + v[1].y + v[2].y + v[3].y + v[4].y;
        float fs2 = v[0].z + v[1].z + v[2].z + v[3].z + v[4].z;
        float fs3 = v[0].w + v[1].w + v[2].w + v[3].w + v[4].w;
        #pragma unroll
        for (int m = 4; m <= 8; m <<= 1) {
            fs0 += __shfl_xor(fs0, m, 16);
            fs1 += __shfl_xor(fs1, m, 16);
            fs2 += __shfl_xor(fs2, m, 16);
            fs3 += __shfl_xor(fs3, m, 16);
        }
        if (lane < 4)
            ((float4*)(f_out + (size_t)node * 16))[lane] = float4{fs0, fs1, fs2, fs3};
    }
}

// ---------------- fused AGNNConv D=16, 16-lane group per node ----------------
// Depth-1 prefetch; self-loop edges reuse dv (no gather).
// EPI: 0 = store + inv norm; 2 = row softmax(acc*inv_temp).
template <int EPI>
__global__ void agnn_small(const float* __restrict__ h,
                           const unsigned* __restrict__ rowstart,
                           const int* __restrict__ esrc,
                           const int* __restrict__ perm,
                           const float* __restrict__ beta,
                           const float* __restrict__ inv_in,
                           float* __restrict__ out,
                           float* __restrict__ inv_out,       // EPI==0
                           float inv_temp,
                           int n) {
    int g    = (blockIdx.x * blockDim.x + threadIdx.x) >> 4;
    int lane = threadIdx.x & 15;
    if (g >= n) return;
    int node = perm[g];
    unsigned r0 = rowstart[node], r1 = rowstart[node + 1];
    float b0 = beta[0];
    float M  = fabsf(b0);
    float bs = b0 * inv_in[node];

    float dv = h[(size_t)node * 16 + lane];
    float acc = 0.f, lrun = 0.f;

    for (unsigned base = r0; base < r1; base += 16) {
        unsigned j = base + (unsigned)lane;
        bool  vld = j < r1;
        int   sv  = vld ? esrc[j] : 0;
        float iv  = vld ? inv_in[sv] : 0.f;
        int cnt = (int)min(r1 - base, 16u);
        int s0 = __shfl(sv, 0, 16);
        bool nself = (s0 == node);
        float rv_next = dv;
        if (!nself) rv_next = h[(size_t)s0 * 16 + lane];
        for (int t = 0; t < cnt; t++) {
            float rv = rv_next;
            if (t + 1 < cnt) {
                int s1 = __shfl(sv, t + 1, 16);
                nself = (s1 == node);
                rv_next = dv;
                if (!nself) rv_next = h[(size_t)s1 * 16 + lane];
            }
            float ins = __shfl(iv, t, 16);
            float dt = rv * dv;
            #pragma unroll
            for (int m = 8; m >= 1; m >>= 1) dt += __shfl_xor(dt, m, 16);
            float w = __expf(bs * ins * dt - M);
            lrun += w;
            acc += w * rv;
        }
    }
    float val = acc / lrun;

    if (EPI == 0) {
        out[(size_t)node * 16 + lane] = val;
        float s2 = val * val;
        #pragma unroll
        for (int m = 8; m >= 1; m >>= 1) s2 += __shfl_xor(s2, m, 16);
        if (lane == 0) inv_out[node] = 1.f / fmaxf(sqrtf(s2), 1e-12f);
    } else {
        float v2 = val * inv_temp;
        float mx = v2;
        #pragma unroll
        for (int m = 8; m >= 1; m >>= 1) mx = fmaxf(mx, __shfl_xor(mx, m, 16));
        float ee = __expf(v2 - mx);
        float ss = ee;
        #pragma unroll
        for (int m = 8; m >= 1; m >>= 1) ss += __shfl_xor(ss, m, 16);
        out[(size_t)node * 16 + lane] = ee / ss;
    }
}

// ---------------- BatchNorm stats ----------------
__global__ void bn_reduce(const float* __restrict__ f, float* __restrict__ stats, int n) {
    int c = threadIdx.x & 15;
    int g = threadIdx.x >> 4;
    float s = 0.f, s2 = 0.f;
    for (int i = blockIdx.x * 16 + g; i < n; i += gridDim.x * 16) {
        float v = f[(size_t)i * 16 + c];
        s += v; s2 += v * v;
    }
    __shared__ float ls[256], ls2[256];
    ls[threadIdx.x] = s; ls2[threadIdx.x] = s2;
    __syncthreads();
    for (int off = 128; off >= 16; off >>= 1) {
        if ((int)threadIdx.x < off) {
            ls[threadIdx.x]  += ls[threadIdx.x + off];
            ls2[threadIdx.x] += ls2[threadIdx.x + off];
        }
        __syncthreads();
    }
    if (threadIdx.x < 16) {
        atomicAdd(&stats[threadIdx.x], ls[threadIdx.x]);
        atomicAdd(&stats[16 + threadIdx.x], ls2[threadIdx.x]);
    }
}

// ------- BN finalize+apply + LeakyReLU + softmax(f*10) @ rc + inv-norm(f) ----
// Finalize (mean/var -> scale/shift) recomputed per block from raw stats.
// rc held in 80 per-lane registers (lane L owns columns d = L + 64u, u<5).
__global__ void __launch_bounds__(256)
bn_apply_p(float* __restrict__ f, const float* __restrict__ stats,
           const float* __restrict__ bnw, const float* __restrict__ bnb,
           const float* __restrict__ rc, float* __restrict__ p,
           float* __restrict__ invf, int n) {
    __shared__ float s_sc[16], s_sh[16];
    if (threadIdx.x < 16) {
        int c = threadIdx.x;
        float mean  = stats[c] / (float)n;
        float var   = fmaxf(stats[16 + c] / (float)n - mean * mean, 0.f);
        float scale = bnw[c] / sqrtf(var + 1e-5f);
        s_sc[c] = scale;
        s_sh[c] = bnb[c] - mean * scale;
    }
    __syncthreads();

    int lane = threadIdx.x & 63;

    // per-lane rc fragment: rcw[c][u] = rc[c*320 + lane + 64u] (static idx only)
    float rcw[16][5];
    #pragma unroll
    for (int c = 0; c < 16; c++) {
        #pragma unroll
        for (int u = 0; u < 5; u++) rcw[c][u] = rc[c * D_BIG + lane + 64 * u];
    }

    int wave = (blockIdx.x * blockDim.x + threadIdx.x) >> 6;
    int nw   = (gridDim.x * blockDim.x) >> 6;

    for (int i = wave; i < n; i += nw) {
        const float* fr = f + (size_t)i * 16;
        float fv[16];
        float mx = -1e30f;
        #pragma unroll
        for (int c = 0; c < 16; c++) {
            float v = fmaf(fr[c], s_sc[c], s_sh[c]);
            v = (v >= 0.f) ? v : 0.25f * v;           // LeakyReLU(0.25)
            fv[c] = v;
            mx = fmaxf(mx, v);
        }
        // store-back with static indexing: lanes<16 recompute their own channel
        if (lane < 16) {
            float v = fmaf(fr[lane], s_sc[lane], s_sh[lane]);
            v = (v >= 0.f) ? v : 0.25f * v;
            f[(size_t)i * 16 + lane] = v;
        }

        float s2 = 0.f;
        #pragma unroll
        for (int c = 0; c < 16; c++) s2 += fv[c] * fv[c];
        if (lane == 0) invf[i] = 1.f / fmaxf(sqrtf(s2), 1e-12f);

        float sp[16]; float sum = 0.f;
        #pragma unroll
        for (int c = 0; c < 16; c++) { float t = __expf((fv[c] - mx) * 10.0f); sp[c] = t; sum += t; }
        float isum = 1.f / sum;

        #pragma unroll
        for (int u = 0; u < 5; u++) {
            float acc0 = 0.f, acc1 = 0.f;      // dual partials: shorter dep chain
            #pragma unroll
            for (int c = 0; c < 16; c += 2) {
                acc0 = fmaf(sp[c],     rcw[c][u],     acc0);
                acc1 = fmaf(sp[c + 1], rcw[c + 1][u], acc1);
            }
            p[(size_t)i * D_BIG + lane + 64 * u] = (acc0 + acc1) * isum;
        }
    }
}

extern "C" void kernel_launch(void* const* d_in, const int* in_sizes, int n_in,
                              void* d_out, int out_size, void* d_ws, size_t ws_size,
                              hipStream_t stream) {
    const float* x    = (const float*)d_in[0];
    const int*   src  = (const int*)d_in[1];
    const int*   dst  = (const int*)d_in[2];
    const float* mw   = (const float*)d_in[3];
    const float* bnw  = (const float*)d_in[4];
    const float* bnb  = (const float*)d_in[5];
    const float* rc   = (const float*)d_in[6];
    const float* beta = (const float*)d_in[7];

    const int n  = in_sizes[0] / D_BIG;   // 50000
    const int nE = in_sizes[1];           // 300000

    float* out     = (float*)d_out;
    float* fea_out = out;                          // N*320
    float* f_out   = out + (size_t)n * D_BIG;      // N*16
    float* p_out   = f_out + (size_t)n * 16;       // N*320
    float* o_out   = p_out + (size_t)n * D_BIG;    // N*16

    // fp16 staging parked inside output regions that are dead at that point:
    //   xh  (32MB fp16 x)  -> fea_out region (fea written only by conv2 epilogue)
    //   h1h (32MB fp16 h1) -> p_out region   (p written only by bn_apply_p)
    uint2* xh  = (uint2*)fea_out;
    uint2* h1h = (uint2*)p_out;

    const int TB = 256;
    auto cdiv = [](int a, int b) { return (a + b - 1) / b; };
    const int nb   = cdiv(n, 256);   // 196 (<=256 required by the scans)
    const int nbE  = cdiv(nE, 256);  // edge blocks for scatter
    const int ngrp = cdiv(n, 16);    // blocks for 16-lane-group kernels

    // workspace carve (~6.3 MB)
    char* w = (char*)d_ws;
    auto carve = [&](size_t bytes) { void* r = (void*)w; w += (bytes + 255) & ~(size_t)255; return r; };
    unsigned* deg       = (unsigned*)carve((size_t)n * 4);
    unsigned* rowstart  = (unsigned*)carve((size_t)(n + 1) * 4);
    unsigned* cursor    = (unsigned*)carve((size_t)n * 4);
    unsigned* bsum      = (unsigned*)carve(256 * 4);
    int*      esrc      = (int*)carve((size_t)nE * 4);
    float*    stats     = (float*)carve(64 * 4);
    float*    t16       = (float*)carve((size_t)n * 16 * 4);
    int*      perm      = (int*)carve((size_t)n * 4);
    unsigned* blockhist = (unsigned*)carve((size_t)64 * nb * 4);
    unsigned* btot      = (unsigned*)carve(64 * 4);
    float*    inv_x     = (float*)carve((size_t)n * 4);
    float*    inv_h1    = (float*)carve((size_t)n * 4);
    float*    inv_f     = (float*)carve((size_t)n * 4);
    float*    inv_t     = (float*)carve((size_t)n * 4);

    // CSR build + LPT counting sort (13 launches total for the whole net)
    fill_u32<<<cdiv(n, TB), TB, 0, stream>>>(deg, 0u, n);
    count_deg<<<cdiv(nE, TB), TB, 0, stream>>>(dst, deg, nE);
    scan1<<<nb, 256, 0, stream>>>(deg, rowstart, bsum, blockhist, cursor, stats, n, nb);
    scan2b<<<65, 256, 0, stream>>>(bsum, blockhist, btot, nb);
    scan3b<<<nb + 1, 256, 0, stream>>>(rowstart, bsum, btot, n, nE, nb);
    scatter_place<<<nbE + nb, 256, 0, stream>>>(src, dst, rowstart, cursor, esrc,
                                                deg, blockhist, btot, perm,
                                                nE, n, nb, nbE);

    // inv-norm of x + f32->fp16 cast (xh)
    prep_x<<<ngrp, TB, 0, stream>>>(x, xh, inv_x, n);
    // conv1: xh -> h1h (fp16) + inv_h1
    agnn_big<0><<<ngrp, TB, 0, stream>>>(xh, rowstart, esrc, perm, beta, inv_x,
                                         nullptr, nullptr, h1h, inv_h1, nullptr, n);
    // conv2 + marker + f: h1h -> fea_out (f32, overwrites dead xh), f_out
    agnn_big<1><<<ngrp, TB, 0, stream>>>(h1h, rowstart, esrc, perm, beta, inv_h1,
                                         mw, fea_out, nullptr, nullptr, f_out, n);
    // BatchNorm stats (training-mode)
    bn_reduce<<<128, TB, 0, stream>>>(f_out, stats, n);
    // BN finalize+apply + LeakyReLU (f in place) + p = softmax(f*10) @ rc + inv_f
    bn_apply_p<<<1024, TB, 0, stream>>>(f_out, stats, bnw, bnb, rc, p_out, inv_f, n);
    // conv3: f -> t16 + inv_t
    agnn_small<0><<<ngrp, TB, 0, stream>>>(f_out, rowstart, esrc, perm, beta, inv_f,
                                           t16, inv_t, 0.f, n);
    // conv4 + softmax(/T2): t16 -> o_out
    agnn_small<2><<<ngrp, TB, 0, stream>>>(t16, rowstart, esrc, perm, beta, inv_t,
                                           o_out, nullptr, 0.2f, n);
}